// Round 2
// 3018.768 us; speedup vs baseline: 1.0385x; 1.0385x over previous
//
#include <hip/hip_runtime.h>
#include <stdint.h>

#define D 512
#define VOCAB 256
#define NLAYER 12
#define BB 8
#define SS 8192
#define CH 128          // scan chunks per sequence (SL=64)
#define SL 64

typedef __bf16 bf16x8 __attribute__((ext_vector_type(8)));
typedef float f32x4 __attribute__((ext_vector_type(4)));
typedef _Float16 half2_t __attribute__((ext_vector_type(2)));

__device__ __forceinline__ unsigned short f2bf(float f) {
  union { float f; uint32_t u; } c; c.f = f;
  uint32_t u = c.u;
  u += 0x7FFFu + ((u >> 16) & 1u);   // RNE
  return (unsigned short)(u >> 16);
}

__device__ __forceinline__ float rcpf_(float x) { return __builtin_amdgcn_rcpf(x); }

__device__ __forceinline__ uint32_t pack_fv(float f, float v) {
  union { half2_t h; uint32_t u; } c;
  c.h.x = (_Float16)f;
  c.h.y = (_Float16)v;
  return c.u;
}

__device__ __forceinline__ void unpack_fv(uint32_t u, float& f, float& v) {
  union { uint32_t u; half2_t h; } c; c.u = u;
  f = (float)c.h.x;
  v = (float)c.h.y;
}

__device__ __forceinline__ void gl_lds16(const unsigned short* g, unsigned short* l) {
  __builtin_amdgcn_global_load_lds((const __attribute__((address_space(1))) void*)(const void*)g,
                                   (__attribute__((address_space(3))) void*)(void*)l, 16, 0, 0);
}

// ---------------- embedding gather + FUSED layer-0 LayerNorm -----------------
// Each wave owns one full row (64 lanes x 8 floats = 512): write x AND the
// LN'd bf16 row for layer 0's k_gemm_act (replaces the first k_ln).
__global__ __launch_bounds__(256) void k_gather(const int* __restrict__ toks,
                                                const float* __restrict__ emb,
                                                const float* __restrict__ g,
                                                const float* __restrict__ b,
                                                float* __restrict__ x,
                                                unsigned short* __restrict__ o) {
  int T = blockIdx.x * 256 + threadIdx.x;
  int row = T >> 6, lane = T & 63;
  int tok = toks[row] & (VOCAB - 1);
  const float4* s = (const float4*)(emb + (size_t)tok * D) + lane * 2;
  float4 v0 = s[0], v1 = s[1];
  float4* d = (float4*)(x + (size_t)row * D) + lane * 2;
  d[0] = v0;
  d[1] = v1;
  // LN with layer-0 gamma/beta
  float sm = v0.x + v0.y + v0.z + v0.w + v1.x + v1.y + v1.z + v1.w;
  float ss = v0.x * v0.x + v0.y * v0.y + v0.z * v0.z + v0.w * v0.w +
             v1.x * v1.x + v1.y * v1.y + v1.z * v1.z + v1.w * v1.w;
  for (int m = 32; m; m >>= 1) {
    sm += __shfl_xor(sm, m, 64);
    ss += __shfl_xor(ss, m, 64);
  }
  float mu = sm * (1.0f / 512.0f);
  float var = ss * (1.0f / 512.0f) - mu * mu;
  float rstd = rsqrtf(var + 1e-5f);
  const float4* gp = (const float4*)g + lane * 2;
  const float4* bp = (const float4*)b + lane * 2;
  float4 g0 = gp[0], g1 = gp[1], b0 = bp[0], b1 = bp[1];
  uint32_t w0 = (uint32_t)f2bf((v0.x - mu) * rstd * g0.x + b0.x) |
                ((uint32_t)f2bf((v0.y - mu) * rstd * g0.y + b0.y) << 16);
  uint32_t w1 = (uint32_t)f2bf((v0.z - mu) * rstd * g0.z + b0.z) |
                ((uint32_t)f2bf((v0.w - mu) * rstd * g0.w + b0.w) << 16);
  uint32_t w2 = (uint32_t)f2bf((v1.x - mu) * rstd * g1.x + b1.x) |
                ((uint32_t)f2bf((v1.y - mu) * rstd * g1.y + b1.y) << 16);
  uint32_t w3 = (uint32_t)f2bf((v1.z - mu) * rstd * g1.z + b1.z) |
                ((uint32_t)f2bf((v1.w - mu) * rstd * g1.w + b1.w) << 16);
  uint4 r; r.x = w0; r.y = w1; r.z = w2; r.w = w3;
  ((uint4*)(o + (size_t)row * D))[lane] = r;
}

// ---------------- W (L,512,1024) fp32 -> Wtrow (L,1024,512) bf16 -------------
__global__ __launch_bounds__(256) void k_convW(const float* __restrict__ W,
                                               unsigned short* __restrict__ Wt) {
  __shared__ float tile[32][33];
  int bid = blockIdx.x;
  int l = bid >> 9;
  int rem = bid & 511;
  int kt = rem >> 5, nt = rem & 31;
  int k0 = kt * 32, n0 = nt * 32;
  int tx = threadIdx.x & 31, ty = threadIdx.x >> 5;   // 32 x 8
  const float* Wl = W + (size_t)l * D * 2 * D;
  for (int i = 0; i < 4; i++) {
    int k = k0 + ty + 8 * i;
    tile[ty + 8 * i][tx] = Wl[(size_t)k * 1024 + n0 + tx];
  }
  __syncthreads();
  unsigned short* Wtl = Wt + (size_t)l * 1024 * D;
  for (int i = 0; i < 4; i++) {
    int n = n0 + ty + 8 * i;
    Wtl[(size_t)n * D + k0 + tx] = f2bf(tile[tx][ty + 8 * i]);
  }
}

// ---------------- Wtrow -> B-fragment-ordered WtF ----------------------------
// WtF[l][(n16*16+kt)*64 + lane][e] = Wtrow[l][n16*16 + (lane&15)][kt*32 + (lane>>4)*8 + e]
__global__ __launch_bounds__(256) void k_fragW(const unsigned short* __restrict__ Wt,
                                               unsigned short* __restrict__ WtF) {
  int t = blockIdx.x * 256 + threadIdx.x;
  int lane = t & 63;
  int tile = t >> 6;                 // 0 .. 12*1024-1
  int l = tile >> 10;
  int rem = tile & 1023;
  int n16 = rem >> 4, kt = rem & 15;
  const unsigned short* src = Wt + (size_t)l * 1024 * 512 +
                              (size_t)(n16 * 16 + (lane & 15)) * 512 + kt * 32 + (lane >> 4) * 8;
  *(uint4*)(WtF + (size_t)l * 524288 + ((size_t)rem * 64 + lane) * 8) = *(const uint4*)src;
}

// ---------------- emb fp32 -> bf16 (row-major, for logits GEMM) --------------
__global__ __launch_bounds__(256) void k_convEmb(const float* __restrict__ e,
                                                 unsigned short* __restrict__ o) {
  int t = blockIdx.x * 256 + threadIdx.x;
  const float4* s = (const float4*)e + (size_t)t * 2;
  float4 a = s[0], b = s[1];
  uint32_t w0 = (uint32_t)f2bf(a.x) | ((uint32_t)f2bf(a.y) << 16);
  uint32_t w1 = (uint32_t)f2bf(a.z) | ((uint32_t)f2bf(a.w) << 16);
  uint32_t w2 = (uint32_t)f2bf(b.x) | ((uint32_t)f2bf(b.y) << 16);
  uint32_t w3 = (uint32_t)f2bf(b.z) | ((uint32_t)f2bf(b.w) << 16);
  uint4 r; r.x = w0; r.y = w1; r.z = w2; r.w = w3;
  ((uint4*)o)[t] = r;
}

// ---------------- mega GEMM + activation + chunk-scan summary ----------------
// (byte-identical to the verified round-0 kernel)
__global__ __launch_bounds__(256, 2) void k_gemm_act(const unsigned short* __restrict__ A,
                                                     const unsigned short* __restrict__ Bt,
                                                     uint32_t* __restrict__ fv,
                                                     float* __restrict__ P,
                                                     float* __restrict__ Q) {
  __shared__ __align__(16) unsigned short As[64 * 512];   // 64 KiB
  const int tid = threadIdx.x;
  const int lane = tid & 63;
  const int wave = tid >> 6;
  const int m0 = blockIdx.x * 64;
  const int qm = lane & 15;
  const int hi = lane >> 4;          // 0..3
  // ---- stage A: one row per inst, chunk-swizzled (cl = cg&~7 | (cg&7)^(r&7))
  for (int j = 0; j < 16; j++) {
    int r = wave * 16 + j;
    int cg = (lane & ~7) | ((lane & 7) ^ (r & 7));
    gl_lds16(A + (size_t)(m0 + r) * 512 + cg * 8, As + r * 512);
  }
  __syncthreads();

  const int b_loc = m0 >> 13;              // batch within group
  const int c_chunk = (m0 & (SS - 1)) >> 6;
  const size_t pq0 = ((size_t)b_loc * CH + c_chunk) * 512;

  for (int np = 0; np < 2; np++) {
    const int c0 = np * 256 + wave * 64;   // hidden col base for this wave
    const int n16h = (c0 >> 4);            // + j ; gate = +32
    f32x4 ah[4][4] = {};
    f32x4 ag[4][4] = {};
    bf16x8 bh[2][4], bg[2][4];
    for (int j = 0; j < 4; j++) {
      bh[0][j] = *(const bf16x8*)(Bt + (((size_t)(n16h + j) * 16 + 0) * 64 + lane) * 8);
      bg[0][j] = *(const bf16x8*)(Bt + (((size_t)(n16h + j + 32) * 16 + 0) * 64 + lane) * 8);
    }
    for (int kt = 0; kt < 16; kt++) {
      const int cur = kt & 1;
      if (kt < 15) {
        const int nxt = cur ^ 1;
        for (int j = 0; j < 4; j++) {
          bh[nxt][j] = *(const bf16x8*)(Bt + (((size_t)(n16h + j) * 16 + kt + 1) * 64 + lane) * 8);
          bg[nxt][j] = *(const bf16x8*)(Bt + (((size_t)(n16h + j + 32) * 16 + kt + 1) * 64 + lane) * 8);
        }
      }
      bf16x8 af[4];
      for (int i = 0; i < 4; i++) {
        int row = i * 16 + qm;
        int cgd = kt * 4 + hi;
        int cl = (cgd & ~7) | ((cgd & 7) ^ (row & 7));
        af[i] = *(const bf16x8*)(&As[row * 512 + cl * 8]);
      }
      for (int i = 0; i < 4; i++)
        for (int j = 0; j < 4; j++) {
          ah[i][j] = __builtin_amdgcn_mfma_f32_16x16x32_bf16(af[i], bh[cur][j], ah[i][j], 0, 0, 0);
          ag[i][j] = __builtin_amdgcn_mfma_f32_16x16x32_bf16(af[i], bg[cur][j], ag[i][j], 0, 0, 0);
        }
    }
    // ---- epilogue: activation + fv store + (P,Q) chunk summary
    const int rq = hi * 4;
    for (int j = 0; j < 4; j++) {
      float cp = 1.f, cq = 0.f;
      for (int i = 0; i < 4; i++) {
        float sp = 1.f, sq = 0.f;
        for (int r = 0; r < 4; r++) {
          float h = ah[i][j][r];
          float g = ag[i][j][r];
          float e = __expf(g);
          float f = rcpf_(1.0f + e);
          float sg = 1.0f - f;
          float gf = h >= 0.0f ? h + 0.5f : rcpf_(1.0f + __expf(-h));
          float v = sg * gf;
          int rowg = m0 + i * 16 + rq + r;
          fv[(size_t)rowg * 512 + c0 + j * 16 + qm] = pack_fv(f, v);
          sp *= f;
          sq = sq * f + v;
        }
        // ordered combine across hi groups (rows i*16 + hi*4 + r)
        float op = __shfl_xor(sp, 16), oq = __shfl_xor(sq, 16);
        float tp = sp * op;
        float tq = (lane & 16) ? (oq * sp + sq) : (sq * op + oq);
        op = __shfl_xor(tp, 32); oq = __shfl_xor(tq, 32);
        sp = tp * op;
        sq = (lane & 32) ? (oq * tp + tq) : (tq * op + oq);
        // compose chunk (i ascending = row ascending)
        cq = cq * sp + sq;
        cp = cp * sp;
      }
      if (hi == 0) {
        P[pq0 + c0 + j * 16 + qm] = cp;
        Q[pq0 + c0 + j * 16 + qm] = cq;
      }
    }
  }
}

// ---------------- logits GEMM (round-5 structure): C = A * Bt^T --------------
__global__ __launch_bounds__(256) void k_gemm(const unsigned short* __restrict__ A,
                                              const unsigned short* __restrict__ Bt,
                                              float* __restrict__ C, int N, int MT) {
  __shared__ __align__(16) unsigned short As[128 * 64];
  __shared__ __align__(16) unsigned short Bs[128 * 64];
  const int tid = threadIdx.x;
  const int lane = tid & 63;
  const int wave = tid >> 6;
  const int bid = blockIdx.x;
  const int mt = bid % MT;
  const int nt = bid / MT;
  const int m0 = mt * 128, n0 = nt * 128;
  const int wr = (wave >> 1) * 64;
  const int wc = (wave & 1) * 64;
  const int lrow = lane >> 3;
  const int lcs = ((lane & 7) ^ lrow) * 8;
  const unsigned short* Ag = A + (size_t)(m0 + wave * 32 + lrow) * 512 + lcs;
  const unsigned short* Bg = Bt + (size_t)(n0 + wave * 32 + lrow) * 512 + lcs;
  unsigned short* Al = As + wave * 32 * 64;
  unsigned short* Bl = Bs + wave * 32 * 64;
  const int qm = lane & 15;
  const int hi = lane >> 4;
  f32x4 acc[4][4] = {};
  for (int k0 = 0; k0 < 512; k0 += 64) {
    for (int j = 0; j < 4; j++) gl_lds16(Ag + k0 + (size_t)j * 8 * 512, Al + j * 512);
    for (int j = 0; j < 4; j++) gl_lds16(Bg + k0 + (size_t)j * 8 * 512, Bl + j * 512);
    __syncthreads();
    for (int ks = 0; ks < 2; ks++) {
      const int sw = ((ks * 4 + hi) ^ (qm & 7)) * 8;
      bf16x8 af[4], bfr[4];
      for (int i = 0; i < 4; i++) {
        af[i] = *(const bf16x8*)(&As[(wr + i * 16 + qm) * 64 + sw]);
        bfr[i] = *(const bf16x8*)(&Bs[(wc + i * 16 + qm) * 64 + sw]);
      }
      for (int i = 0; i < 4; i++)
        for (int j = 0; j < 4; j++)
          acc[i][j] = __builtin_amdgcn_mfma_f32_16x16x32_bf16(af[i], bfr[j], acc[i][j], 0, 0, 0);
    }
    __syncthreads();
  }
  const int col = lane & 15;
  const int rq = (lane >> 4) * 4;
  for (int i = 0; i < 4; i++)
    for (int j = 0; j < 4; j++)
      for (int r = 0; r < 4; r++)
        C[(size_t)(m0 + wr + i * 16 + rq + r) * N + (n0 + wc + j * 16 + col)] = acc[i][j][r];
}

// ---------------- scan phase 2: prefix over CH chunks per (b,d) --------------
__global__ __launch_bounds__(256) void k_scan2(const float* __restrict__ P,
                                               const float* __restrict__ Q,
                                               float* __restrict__ Hs) {
  int T = blockIdx.x * 256 + threadIdx.x;  // b*512 + d
  int d = T & 511;
  int b = T >> 9;
  float h = 0.f;
  for (int c = 0; c < CH; c++) {
    size_t i = ((size_t)b * CH + c) * 512 + d;
    Hs[i] = h;
    h = P[i] * h + Q[i];
  }
}

// ---------------- scan phase 3: apply + residual add + FUSED next-layer LN ---
// One block per (b,c) chunk, 512 threads. Phase A: per-column scan + x update
// (identical math to the verified k_scan3). Barrier. Phase B: wave-per-row LN
// (verified k_ln body) over the 64 rows this block just wrote — rows are
// L2-hot — producing hbf for the NEXT consumer (layer l+1's gemm_act, or the
// logits GEMM when g/b = norm_g/norm_b). Replaces the standalone k_ln.
__global__ __launch_bounds__(512) void k_scan3(const uint32_t* __restrict__ fv,
                                               const float* __restrict__ Hs,
                                               float* __restrict__ x,
                                               const float* __restrict__ g,
                                               const float* __restrict__ b,
                                               unsigned short* __restrict__ o) {
  const int d = threadIdx.x;               // 0..511
  const int bc = blockIdx.x;               // b*CH + c
  const int c = bc & (CH - 1);
  const int bb = bc >> 7;                  // CH = 128
  const size_t row0 = ((size_t)bb * SS + (size_t)c * SL);
  const uint32_t* base = fv + row0 * 512 + d;
  float* xb = x + row0 * 512 + d;
  float h = Hs[(size_t)bc * 512 + d];
  for (int s = 0; s < SL; s++) {
    float f, v;
    unpack_fv(base[(size_t)s * 512], f, v);
    h = f * h + v;
    xb[(size_t)s * 512] += h;
  }
  __syncthreads();   // block's x-rows complete & visible (workgroup scope)

  // ---- phase B: LN of the 64 rows, 8 waves x 8 rows, wave-per-row
  const int wv = threadIdx.x >> 6, lane = threadIdx.x & 63;
  const float4* gp = (const float4*)g + lane * 2;
  const float4* bp = (const float4*)b + lane * 2;
  float4 g0 = gp[0], g1 = gp[1], b0 = bp[0], b1 = bp[1];
  const float* xr0 = x + row0 * 512;
  for (int rr = 0; rr < 8; rr++) {
    int r = wv * 8 + rr;
    const float4* xr = (const float4*)(xr0 + (size_t)r * 512) + lane * 2;
    float4 v0 = xr[0], v1 = xr[1];
    float sm = v0.x + v0.y + v0.z + v0.w + v1.x + v1.y + v1.z + v1.w;
    float ss = v0.x * v0.x + v0.y * v0.y + v0.z * v0.z + v0.w * v0.w +
               v1.x * v1.x + v1.y * v1.y + v1.z * v1.z + v1.w * v1.w;
    for (int m = 32; m; m >>= 1) {
      sm += __shfl_xor(sm, m, 64);
      ss += __shfl_xor(ss, m, 64);
    }
    float mu = sm * (1.0f / 512.0f);
    float var = ss * (1.0f / 512.0f) - mu * mu;
    float rstd = rsqrtf(var + 1e-5f);
    uint32_t w0 = (uint32_t)f2bf((v0.x - mu) * rstd * g0.x + b0.x) |
                  ((uint32_t)f2bf((v0.y - mu) * rstd * g0.y + b0.y) << 16);
    uint32_t w1 = (uint32_t)f2bf((v0.z - mu) * rstd * g0.z + b0.z) |
                  ((uint32_t)f2bf((v0.w - mu) * rstd * g0.w + b0.w) << 16);
    uint32_t w2 = (uint32_t)f2bf((v1.x - mu) * rstd * g1.x + b1.x) |
                  ((uint32_t)f2bf((v1.y - mu) * rstd * g1.y + b1.y) << 16);
    uint32_t w3 = (uint32_t)f2bf((v1.z - mu) * rstd * g1.z + b1.z) |
                  ((uint32_t)f2bf((v1.w - mu) * rstd * g1.w + b1.w) << 16);
    uint4 rr4; rr4.x = w0; rr4.y = w1; rr4.z = w2; rr4.w = w3;
    ((uint4*)(o + (row0 + r) * 512))[lane] = rr4;
  }
}

extern "C" void kernel_launch(void* const* d_in, const int* in_sizes, int n_in,
                              void* d_out, int out_size, void* d_ws, size_t ws_size,
                              hipStream_t stream) {
  const int* toks = (const int*)d_in[0];
  const float* emb = (const float*)d_in[1];
  const float* ln_g = (const float*)d_in[2];
  const float* ln_b = (const float*)d_in[3];
  const float* W = (const float*)d_in[4];
  const float* norm_g = (const float*)d_in[5];
  const float* norm_b = (const float*)d_in[6];
  float* out = (float*)d_out;   // fp32 logits

  // Batch-group ladder; ws_size constant across calls -> graph-safe.
  const int gbs[4] = {8, 4, 2, 1};
  int GB = 1;
  for (int i = 0; i < 4; i++) {
    size_t MGv = (size_t)gbs[i] * SS;
    size_t need = MGv * 5120 + 2 * 12582912 + 262144 + (size_t)gbs[i] * 786432;
    if (need <= ws_size) { GB = gbs[i]; break; }
  }
  const int MG = GB * SS;        // rows per group
  const int MT128 = MG / 128;    // 128-row m-tiles (logits gemm)

  char* p = (char*)d_ws;
  float* x = (float*)p;                     p += (size_t)MG * 2048;
  uint32_t* fv = (uint32_t*)p;              p += (size_t)MG * 2048;
  unsigned short* hbf = (unsigned short*)p; p += (size_t)MG * 1024;
  unsigned short* Wtrow = (unsigned short*)p; p += 12582912;
  unsigned short* WtF = (unsigned short*)p;   p += 12582912;
  unsigned short* ebf = (unsigned short*)p;   p += 262144;
  float* P = (float*)p;                     p += (size_t)GB * 262144;
  float* Q = (float*)p;                     p += (size_t)GB * 262144;
  float* Hs = (float*)p;

  k_convW<<<NLAYER * 512, 256, 0, stream>>>(W, Wtrow);
  k_fragW<<<NLAYER * 1024 * 64 / 256, 256, 0, stream>>>(Wtrow, WtF);
  k_convEmb<<<64, 256, 0, stream>>>(emb, ebf);

  for (int g = 0; g < BB / GB; g++) {
    const int* tg = toks + (size_t)g * MG;
    float* outg = out + (size_t)g * MG * VOCAB;

    // gather + LN(layer 0) -> x, hbf
    k_gather<<<MG / 4, 256, 0, stream>>>(tg, emb, ln_g, ln_b, x, hbf);
    for (int l = 0; l < NLAYER; l++) {
      k_gemm_act<<<MG / 64, 256, 0, stream>>>(hbf, WtF + (size_t)l * 524288, fv, P, Q);
      k_scan2<<<GB * 2, 256, 0, stream>>>(P, Q, Hs);
      const float* gn = (l < NLAYER - 1) ? (ln_g + (size_t)(l + 1) * D) : norm_g;
      const float* bn = (l < NLAYER - 1) ? (ln_b + (size_t)(l + 1) * D) : norm_b;
      k_scan3<<<GB * CH, 512, 0, stream>>>(fv, Hs, x, gn, bn, hbf);
    }
    k_gemm<<<2 * MT128, 256, 0, stream>>>(hbf, ebf, outg, VOCAB, MT128);
  }
}

// Round 3
// 2893.815 us; speedup vs baseline: 1.0833x; 1.0432x over previous
//
#include <hip/hip_runtime.h>
#include <stdint.h>

#define D 512
#define VOCAB 256
#define NLAYER 12
#define BB 8
#define SS 8192
#define CH 128          // scan chunks per sequence (SL=64)
#define SL 64

typedef __bf16 bf16x8 __attribute__((ext_vector_type(8)));
typedef float f32x4 __attribute__((ext_vector_type(4)));
typedef _Float16 half2_t __attribute__((ext_vector_type(2)));

__device__ __forceinline__ unsigned short f2bf(float f) {
  union { float f; uint32_t u; } c; c.f = f;
  uint32_t u = c.u;
  u += 0x7FFFu + ((u >> 16) & 1u);   // RNE
  return (unsigned short)(u >> 16);
}

__device__ __forceinline__ float rcpf_(float x) { return __builtin_amdgcn_rcpf(x); }

__device__ __forceinline__ uint32_t pack_fv(float f, float v) {
  union { half2_t h; uint32_t u; } c;
  c.h.x = (_Float16)f;
  c.h.y = (_Float16)v;
  return c.u;
}

__device__ __forceinline__ void unpack_fv(uint32_t u, float& f, float& v) {
  union { uint32_t u; half2_t h; } c; c.u = u;
  f = (float)c.h.x;
  v = (float)c.h.y;
}

__device__ __forceinline__ void gl_lds16(const unsigned short* g, unsigned short* l) {
  __builtin_amdgcn_global_load_lds((const __attribute__((address_space(1))) void*)(const void*)g,
                                   (__attribute__((address_space(3))) void*)(void*)l, 16, 0, 0);
}

// ---------------- embedding gather + FUSED layer-0 LayerNorm -----------------
__global__ __launch_bounds__(256) void k_gather(const int* __restrict__ toks,
                                                const float* __restrict__ emb,
                                                const float* __restrict__ g,
                                                const float* __restrict__ b,
                                                float* __restrict__ x,
                                                unsigned short* __restrict__ o) {
  int T = blockIdx.x * 256 + threadIdx.x;
  int row = T >> 6, lane = T & 63;
  int tok = toks[row] & (VOCAB - 1);
  const float4* s = (const float4*)(emb + (size_t)tok * D) + lane * 2;
  float4 v0 = s[0], v1 = s[1];
  float4* d = (float4*)(x + (size_t)row * D) + lane * 2;
  d[0] = v0;
  d[1] = v1;
  float sm = v0.x + v0.y + v0.z + v0.w + v1.x + v1.y + v1.z + v1.w;
  float ss = v0.x * v0.x + v0.y * v0.y + v0.z * v0.z + v0.w * v0.w +
             v1.x * v1.x + v1.y * v1.y + v1.z * v1.z + v1.w * v1.w;
  for (int m = 32; m; m >>= 1) {
    sm += __shfl_xor(sm, m, 64);
    ss += __shfl_xor(ss, m, 64);
  }
  float mu = sm * (1.0f / 512.0f);
  float var = ss * (1.0f / 512.0f) - mu * mu;
  float rstd = rsqrtf(var + 1e-5f);
  const float4* gp = (const float4*)g + lane * 2;
  const float4* bp = (const float4*)b + lane * 2;
  float4 g0 = gp[0], g1 = gp[1], b0 = bp[0], b1 = bp[1];
  uint32_t w0 = (uint32_t)f2bf((v0.x - mu) * rstd * g0.x + b0.x) |
                ((uint32_t)f2bf((v0.y - mu) * rstd * g0.y + b0.y) << 16);
  uint32_t w1 = (uint32_t)f2bf((v0.z - mu) * rstd * g0.z + b0.z) |
                ((uint32_t)f2bf((v0.w - mu) * rstd * g0.w + b0.w) << 16);
  uint32_t w2 = (uint32_t)f2bf((v1.x - mu) * rstd * g1.x + b1.x) |
                ((uint32_t)f2bf((v1.y - mu) * rstd * g1.y + b1.y) << 16);
  uint32_t w3 = (uint32_t)f2bf((v1.z - mu) * rstd * g1.z + b1.z) |
                ((uint32_t)f2bf((v1.w - mu) * rstd * g1.w + b1.w) << 16);
  uint4 r; r.x = w0; r.y = w1; r.z = w2; r.w = w3;
  ((uint4*)(o + (size_t)row * D))[lane] = r;
}

// ---------------- W (L,512,1024) fp32 -> Wtrow (L,1024,512) bf16 -------------
__global__ __launch_bounds__(256) void k_convW(const float* __restrict__ W,
                                               unsigned short* __restrict__ Wt) {
  __shared__ float tile[32][33];
  int bid = blockIdx.x;
  int l = bid >> 9;
  int rem = bid & 511;
  int kt = rem >> 5, nt = rem & 31;
  int k0 = kt * 32, n0 = nt * 32;
  int tx = threadIdx.x & 31, ty = threadIdx.x >> 5;   // 32 x 8
  const float* Wl = W + (size_t)l * D * 2 * D;
  for (int i = 0; i < 4; i++) {
    int k = k0 + ty + 8 * i;
    tile[ty + 8 * i][tx] = Wl[(size_t)k * 1024 + n0 + tx];
  }
  __syncthreads();
  unsigned short* Wtl = Wt + (size_t)l * 1024 * D;
  for (int i = 0; i < 4; i++) {
    int n = n0 + ty + 8 * i;
    Wtl[(size_t)n * D + k0 + tx] = f2bf(tile[tx][ty + 8 * i]);
  }
}

// ---------------- Wtrow -> B-fragment-ordered WtF ----------------------------
__global__ __launch_bounds__(256) void k_fragW(const unsigned short* __restrict__ Wt,
                                               unsigned short* __restrict__ WtF) {
  int t = blockIdx.x * 256 + threadIdx.x;
  int lane = t & 63;
  int tile = t >> 6;                 // 0 .. 12*1024-1
  int l = tile >> 10;
  int rem = tile & 1023;
  int n16 = rem >> 4, kt = rem & 15;
  const unsigned short* src = Wt + (size_t)l * 1024 * 512 +
                              (size_t)(n16 * 16 + (lane & 15)) * 512 + kt * 32 + (lane >> 4) * 8;
  *(uint4*)(WtF + (size_t)l * 524288 + ((size_t)rem * 64 + lane) * 8) = *(const uint4*)src;
}

// ---------------- emb fp32 -> bf16 (row-major, for logits GEMM) --------------
__global__ __launch_bounds__(256) void k_convEmb(const float* __restrict__ e,
                                                 unsigned short* __restrict__ o) {
  int t = blockIdx.x * 256 + threadIdx.x;
  const float4* s = (const float4*)e + (size_t)t * 2;
  float4 a = s[0], b = s[1];
  uint32_t w0 = (uint32_t)f2bf(a.x) | ((uint32_t)f2bf(a.y) << 16);
  uint32_t w1 = (uint32_t)f2bf(a.z) | ((uint32_t)f2bf(a.w) << 16);
  uint32_t w2 = (uint32_t)f2bf(b.x) | ((uint32_t)f2bf(b.y) << 16);
  uint32_t w3 = (uint32_t)f2bf(b.z) | ((uint32_t)f2bf(b.w) << 16);
  uint4 r; r.x = w0; r.y = w1; r.z = w2; r.w = w3;
  ((uint4*)o)[t] = r;
}

// ---------------- mega GEMM + activation + chunk-scan summary ----------------
// (byte-identical to the verified round-0 kernel)
__global__ __launch_bounds__(256, 2) void k_gemm_act(const unsigned short* __restrict__ A,
                                                     const unsigned short* __restrict__ Bt,
                                                     uint32_t* __restrict__ fv,
                                                     float* __restrict__ P,
                                                     float* __restrict__ Q) {
  __shared__ __align__(16) unsigned short As[64 * 512];   // 64 KiB
  const int tid = threadIdx.x;
  const int lane = tid & 63;
  const int wave = tid >> 6;
  const int m0 = blockIdx.x * 64;
  const int qm = lane & 15;
  const int hi = lane >> 4;          // 0..3
  for (int j = 0; j < 16; j++) {
    int r = wave * 16 + j;
    int cg = (lane & ~7) | ((lane & 7) ^ (r & 7));
    gl_lds16(A + (size_t)(m0 + r) * 512 + cg * 8, As + r * 512);
  }
  __syncthreads();

  const int b_loc = m0 >> 13;              // batch within group
  const int c_chunk = (m0 & (SS - 1)) >> 6;
  const size_t pq0 = ((size_t)b_loc * CH + c_chunk) * 512;

  for (int np = 0; np < 2; np++) {
    const int c0 = np * 256 + wave * 64;   // hidden col base for this wave
    const int n16h = (c0 >> 4);            // + j ; gate = +32
    f32x4 ah[4][4] = {};
    f32x4 ag[4][4] = {};
    bf16x8 bh[2][4], bg[2][4];
    for (int j = 0; j < 4; j++) {
      bh[0][j] = *(const bf16x8*)(Bt + (((size_t)(n16h + j) * 16 + 0) * 64 + lane) * 8);
      bg[0][j] = *(const bf16x8*)(Bt + (((size_t)(n16h + j + 32) * 16 + 0) * 64 + lane) * 8);
    }
    for (int kt = 0; kt < 16; kt++) {
      const int cur = kt & 1;
      if (kt < 15) {
        const int nxt = cur ^ 1;
        for (int j = 0; j < 4; j++) {
          bh[nxt][j] = *(const bf16x8*)(Bt + (((size_t)(n16h + j) * 16 + kt + 1) * 64 + lane) * 8);
          bg[nxt][j] = *(const bf16x8*)(Bt + (((size_t)(n16h + j + 32) * 16 + kt + 1) * 64 + lane) * 8);
        }
      }
      bf16x8 af[4];
      for (int i = 0; i < 4; i++) {
        int row = i * 16 + qm;
        int cgd = kt * 4 + hi;
        int cl = (cgd & ~7) | ((cgd & 7) ^ (row & 7));
        af[i] = *(const bf16x8*)(&As[row * 512 + cl * 8]);
      }
      for (int i = 0; i < 4; i++)
        for (int j = 0; j < 4; j++) {
          ah[i][j] = __builtin_amdgcn_mfma_f32_16x16x32_bf16(af[i], bh[cur][j], ah[i][j], 0, 0, 0);
          ag[i][j] = __builtin_amdgcn_mfma_f32_16x16x32_bf16(af[i], bg[cur][j], ag[i][j], 0, 0, 0);
        }
    }
    const int rq = hi * 4;
    for (int j = 0; j < 4; j++) {
      float cp = 1.f, cq = 0.f;
      for (int i = 0; i < 4; i++) {
        float sp = 1.f, sq = 0.f;
        for (int r = 0; r < 4; r++) {
          float h = ah[i][j][r];
          float g = ag[i][j][r];
          float e = __expf(g);
          float f = rcpf_(1.0f + e);
          float sg = 1.0f - f;
          float gf = h >= 0.0f ? h + 0.5f : rcpf_(1.0f + __expf(-h));
          float v = sg * gf;
          int rowg = m0 + i * 16 + rq + r;
          fv[(size_t)rowg * 512 + c0 + j * 16 + qm] = pack_fv(f, v);
          sp *= f;
          sq = sq * f + v;
        }
        float op = __shfl_xor(sp, 16), oq = __shfl_xor(sq, 16);
        float tp = sp * op;
        float tq = (lane & 16) ? (oq * sp + sq) : (sq * op + oq);
        op = __shfl_xor(tp, 32); oq = __shfl_xor(tq, 32);
        sp = tp * op;
        sq = (lane & 32) ? (oq * tp + tq) : (tq * op + oq);
        cq = cq * sp + sq;
        cp = cp * sp;
      }
      if (hi == 0) {
        P[pq0 + c0 + j * 16 + qm] = cp;
        Q[pq0 + c0 + j * 16 + qm] = cq;
      }
    }
  }
}

// ---------------- logits GEMM: C = A * Bt^T ---------------------------------
__global__ __launch_bounds__(256) void k_gemm(const unsigned short* __restrict__ A,
                                              const unsigned short* __restrict__ Bt,
                                              float* __restrict__ C, int N, int MT) {
  __shared__ __align__(16) unsigned short As[128 * 64];
  __shared__ __align__(16) unsigned short Bs[128 * 64];
  const int tid = threadIdx.x;
  const int lane = tid & 63;
  const int wave = tid >> 6;
  const int bid = blockIdx.x;
  const int mt = bid % MT;
  const int nt = bid / MT;
  const int m0 = mt * 128, n0 = nt * 128;
  const int wr = (wave >> 1) * 64;
  const int wc = (wave & 1) * 64;
  const int lrow = lane >> 3;
  const int lcs = ((lane & 7) ^ lrow) * 8;
  const unsigned short* Ag = A + (size_t)(m0 + wave * 32 + lrow) * 512 + lcs;
  const unsigned short* Bg = Bt + (size_t)(n0 + wave * 32 + lrow) * 512 + lcs;
  unsigned short* Al = As + wave * 32 * 64;
  unsigned short* Bl = Bs + wave * 32 * 64;
  const int qm = lane & 15;
  const int hi = lane >> 4;
  f32x4 acc[4][4] = {};
  for (int k0 = 0; k0 < 512; k0 += 64) {
    for (int j = 0; j < 4; j++) gl_lds16(Ag + k0 + (size_t)j * 8 * 512, Al + j * 512);
    for (int j = 0; j < 4; j++) gl_lds16(Bg + k0 + (size_t)j * 8 * 512, Bl + j * 512);
    __syncthreads();
    for (int ks = 0; ks < 2; ks++) {
      const int sw = ((ks * 4 + hi) ^ (qm & 7)) * 8;
      bf16x8 af[4], bfr[4];
      for (int i = 0; i < 4; i++) {
        af[i] = *(const bf16x8*)(&As[(wr + i * 16 + qm) * 64 + sw]);
        bfr[i] = *(const bf16x8*)(&Bs[(wc + i * 16 + qm) * 64 + sw]);
      }
      for (int i = 0; i < 4; i++)
        for (int j = 0; j < 4; j++)
          acc[i][j] = __builtin_amdgcn_mfma_f32_16x16x32_bf16(af[i], bfr[j], acc[i][j], 0, 0, 0);
    }
    __syncthreads();
  }
  const int col = lane & 15;
  const int rq = (lane >> 4) * 4;
  for (int i = 0; i < 4; i++)
    for (int j = 0; j < 4; j++)
      for (int r = 0; r < 4; r++)
        C[(size_t)(m0 + wr + i * 16 + rq + r) * N + (n0 + wc + j * 16 + col)] = acc[i][j][r];
}

// ---------------- scan phase 2: hierarchical parallel chunk-prefix -----------
// Old version: 16 blocks x 128 serial L2-latency-bound iterations (GPU 94%
// idle). New: grid = GB * (D/64) blocks x 512 threads (8 waves). Block owns
// (batch b, 64 d-columns); wave w owns chunks [16w, 16w+16). Phase 1: each
// wave serially composes its 16 (P,Q) affine maps (coalesced, independent
// addresses -> pipelined). Phase 2: LDS exchange + exclusive prefix over the
// 8 wave partials (h0 = 0 so only the q-part survives). Phase 3: re-walk the
// 16 chunks (L2-hot) storing Hs. Serial depth 128 -> ~39.
__global__ __launch_bounds__(512) void k_scan2(const float* __restrict__ P,
                                               const float* __restrict__ Q,
                                               float* __restrict__ Hs) {
  __shared__ float lp[8][64];
  __shared__ float lq[8][64];
  const int lane = threadIdx.x & 63;
  const int w = threadIdx.x >> 6;          // 0..7
  const int dg = blockIdx.x & 7;           // d-group (D/64 = 8)
  const int b = blockIdx.x >> 3;
  const int d = dg * 64 + lane;
  const int c0 = w * 16;                   // CH/8 = 16 chunks per wave
  const size_t base = (size_t)b * CH * 512 + d;
  // phase 1: compose this wave's 16 chunks
  float p = 1.f, q = 0.f;
  for (int c = c0; c < c0 + 16; c++) {
    size_t i = base + (size_t)c * 512;
    float Pc = P[i], Qc = Q[i];
    q = q * Pc + Qc;
    p = p * Pc;
  }
  lp[w][lane] = p;
  lq[w][lane] = q;
  __syncthreads();
  // phase 2: exclusive prefix over waves (ascending chunk order)
  float qq = 0.f, pp = 1.f;
  for (int ww = 0; ww < w; ww++) {
    float a = lp[ww][lane], bq = lq[ww][lane];
    qq = qq * a + bq;
    pp = pp * a;
  }
  // phase 3: apply within this wave's range
  float h = qq;                            // h entering chunk c0 (h_init = 0)
  for (int c = c0; c < c0 + 16; c++) {
    size_t i = base + (size_t)c * 512;
    Hs[i] = h;
    h = P[i] * h + Q[i];
  }
  (void)pp;
}

// ---------------- scan phase 3: apply + residual add + FUSED next-layer LN ---
__global__ __launch_bounds__(512) void k_scan3(const uint32_t* __restrict__ fv,
                                               const float* __restrict__ Hs,
                                               float* __restrict__ x,
                                               const float* __restrict__ g,
                                               const float* __restrict__ b,
                                               unsigned short* __restrict__ o) {
  const int d = threadIdx.x;               // 0..511
  const int bc = blockIdx.x;               // b*CH + c
  const int c = bc & (CH - 1);
  const int bb = bc >> 7;                  // CH = 128
  const size_t row0 = ((size_t)bb * SS + (size_t)c * SL);
  const uint32_t* base = fv + row0 * 512 + d;
  float* xb = x + row0 * 512 + d;
  float h = Hs[(size_t)bc * 512 + d];
  for (int s = 0; s < SL; s++) {
    float f, v;
    unpack_fv(base[(size_t)s * 512], f, v);
    h = f * h + v;
    xb[(size_t)s * 512] += h;
  }
  __syncthreads();   // block's x-rows complete & visible (workgroup scope)

  const int wv = threadIdx.x >> 6, lane = threadIdx.x & 63;
  const float4* gp = (const float4*)g + lane * 2;
  const float4* bp = (const float4*)b + lane * 2;
  float4 g0 = gp[0], g1 = gp[1], b0 = bp[0], b1 = bp[1];
  const float* xr0 = x + row0 * 512;
  for (int rr = 0; rr < 8; rr++) {
    int r = wv * 8 + rr;
    const float4* xr = (const float4*)(xr0 + (size_t)r * 512) + lane * 2;
    float4 v0 = xr[0], v1 = xr[1];
    float sm = v0.x + v0.y + v0.z + v0.w + v1.x + v1.y + v1.z + v1.w;
    float ss = v0.x * v0.x + v0.y * v0.y + v0.z * v0.z + v0.w * v0.w +
               v1.x * v1.x + v1.y * v1.y + v1.z * v1.z + v1.w * v1.w;
    for (int m = 32; m; m >>= 1) {
      sm += __shfl_xor(sm, m, 64);
      ss += __shfl_xor(ss, m, 64);
    }
    float mu = sm * (1.0f / 512.0f);
    float var = ss * (1.0f / 512.0f) - mu * mu;
    float rstd = rsqrtf(var + 1e-5f);
    uint32_t w0 = (uint32_t)f2bf((v0.x - mu) * rstd * g0.x + b0.x) |
                  ((uint32_t)f2bf((v0.y - mu) * rstd * g0.y + b0.y) << 16);
    uint32_t w1 = (uint32_t)f2bf((v0.z - mu) * rstd * g0.z + b0.z) |
                  ((uint32_t)f2bf((v0.w - mu) * rstd * g0.w + b0.w) << 16);
    uint32_t w2 = (uint32_t)f2bf((v1.x - mu) * rstd * g1.x + b1.x) |
                  ((uint32_t)f2bf((v1.y - mu) * rstd * g1.y + b1.y) << 16);
    uint32_t w3 = (uint32_t)f2bf((v1.z - mu) * rstd * g1.z + b1.z) |
                  ((uint32_t)f2bf((v1.w - mu) * rstd * g1.w + b1.w) << 16);
    uint4 rr4; rr4.x = w0; rr4.y = w1; rr4.z = w2; rr4.w = w3;
    ((uint4*)(o + (row0 + r) * 512))[lane] = rr4;
  }
}

extern "C" void kernel_launch(void* const* d_in, const int* in_sizes, int n_in,
                              void* d_out, int out_size, void* d_ws, size_t ws_size,
                              hipStream_t stream) {
  const int* toks = (const int*)d_in[0];
  const float* emb = (const float*)d_in[1];
  const float* ln_g = (const float*)d_in[2];
  const float* ln_b = (const float*)d_in[3];
  const float* W = (const float*)d_in[4];
  const float* norm_g = (const float*)d_in[5];
  const float* norm_b = (const float*)d_in[6];
  float* out = (float*)d_out;   // fp32 logits

  // Batch-group ladder; ws_size constant across calls -> graph-safe.
  const int gbs[4] = {8, 4, 2, 1};
  int GB = 1;
  for (int i = 0; i < 4; i++) {
    size_t MGv = (size_t)gbs[i] * SS;
    size_t need = MGv * 5120 + 2 * 12582912 + 262144 + (size_t)gbs[i] * 786432;
    if (need <= ws_size) { GB = gbs[i]; break; }
  }
  const int MG = GB * SS;        // rows per group
  const int MT128 = MG / 128;    // 128-row m-tiles (logits gemm)

  char* p = (char*)d_ws;
  float* x = (float*)p;                     p += (size_t)MG * 2048;
  uint32_t* fv = (uint32_t*)p;              p += (size_t)MG * 2048;
  unsigned short* hbf = (unsigned short*)p; p += (size_t)MG * 1024;
  unsigned short* Wtrow = (unsigned short*)p; p += 12582912;
  unsigned short* WtF = (unsigned short*)p;   p += 12582912;
  unsigned short* ebf = (unsigned short*)p;   p += 262144;
  float* P = (float*)p;                     p += (size_t)GB * 262144;
  float* Q = (float*)p;                     p += (size_t)GB * 262144;
  float* Hs = (float*)p;

  k_convW<<<NLAYER * 512, 256, 0, stream>>>(W, Wtrow);
  k_fragW<<<NLAYER * 1024 * 64 / 256, 256, 0, stream>>>(Wtrow, WtF);
  k_convEmb<<<64, 256, 0, stream>>>(emb, ebf);

  for (int g = 0; g < BB / GB; g++) {
    const int* tg = toks + (size_t)g * MG;
    float* outg = out + (size_t)g * MG * VOCAB;

    // gather + LN(layer 0) -> x, hbf
    k_gather<<<MG / 4, 256, 0, stream>>>(tg, emb, ln_g, ln_b, x, hbf);
    for (int l = 0; l < NLAYER; l++) {
      k_gemm_act<<<MG / 64, 256, 0, stream>>>(hbf, WtF + (size_t)l * 524288, fv, P, Q);
      k_scan2<<<GB * 8, 512, 0, stream>>>(P, Q, Hs);
      const float* gn = (l < NLAYER - 1) ? (ln_g + (size_t)(l + 1) * D) : norm_g;
      const float* bn = (l < NLAYER - 1) ? (ln_b + (size_t)(l + 1) * D) : norm_b;
      k_scan3<<<GB * CH, 512, 0, stream>>>(fv, Hs, x, gn, bn, hbf);
    }
    k_gemm<<<2 * MT128, 256, 0, stream>>>(hbf, ebf, outg, VOCAB, MT128);
  }
}

// Round 4
// 2672.549 us; speedup vs baseline: 1.1730x; 1.0828x over previous
//
#include <hip/hip_runtime.h>
#include <stdint.h>

#define D 512
#define VOCAB 256
#define NLAYER 12
#define BB 8
#define SS 8192
#define CH 128          // scan chunks per sequence (SL=64)
#define SL 64

typedef __bf16 bf16x8 __attribute__((ext_vector_type(8)));
typedef float f32x4 __attribute__((ext_vector_type(4)));
typedef _Float16 half2_t __attribute__((ext_vector_type(2)));

__device__ __forceinline__ unsigned short f2bf(float f) {
  union { float f; uint32_t u; } c; c.f = f;
  uint32_t u = c.u;
  u += 0x7FFFu + ((u >> 16) & 1u);   // RNE
  return (unsigned short)(u >> 16);
}

__device__ __forceinline__ float rcpf_(float x) { return __builtin_amdgcn_rcpf(x); }

__device__ __forceinline__ uint32_t pack_fv(float f, float v) {
  union { half2_t h; uint32_t u; } c;
  c.h.x = (_Float16)f;
  c.h.y = (_Float16)v;
  return c.u;
}

__device__ __forceinline__ void unpack_fv(uint32_t u, float& f, float& v) {
  union { uint32_t u; half2_t h; } c; c.u = u;
  f = (float)c.h.x;
  v = (float)c.h.y;
}

__device__ __forceinline__ void gl_lds16(const unsigned short* g, unsigned short* l) {
  __builtin_amdgcn_global_load_lds((const __attribute__((address_space(1))) void*)(const void*)g,
                                   (__attribute__((address_space(3))) void*)(void*)l, 16, 0, 0);
}

// ---------------- embedding gather + FUSED layer-0 LayerNorm -----------------
__global__ __launch_bounds__(256) void k_gather(const int* __restrict__ toks,
                                                const float* __restrict__ emb,
                                                const float* __restrict__ g,
                                                const float* __restrict__ b,
                                                float* __restrict__ x,
                                                unsigned short* __restrict__ o) {
  int T = blockIdx.x * 256 + threadIdx.x;
  int row = T >> 6, lane = T & 63;
  int tok = toks[row] & (VOCAB - 1);
  const float4* s = (const float4*)(emb + (size_t)tok * D) + lane * 2;
  float4 v0 = s[0], v1 = s[1];
  float4* d = (float4*)(x + (size_t)row * D) + lane * 2;
  d[0] = v0;
  d[1] = v1;
  float sm = v0.x + v0.y + v0.z + v0.w + v1.x + v1.y + v1.z + v1.w;
  float ss = v0.x * v0.x + v0.y * v0.y + v0.z * v0.z + v0.w * v0.w +
             v1.x * v1.x + v1.y * v1.y + v1.z * v1.z + v1.w * v1.w;
  for (int m = 32; m; m >>= 1) {
    sm += __shfl_xor(sm, m, 64);
    ss += __shfl_xor(ss, m, 64);
  }
  float mu = sm * (1.0f / 512.0f);
  float var = ss * (1.0f / 512.0f) - mu * mu;
  float rstd = rsqrtf(var + 1e-5f);
  const float4* gp = (const float4*)g + lane * 2;
  const float4* bp = (const float4*)b + lane * 2;
  float4 g0 = gp[0], g1 = gp[1], b0 = bp[0], b1 = bp[1];
  uint32_t w0 = (uint32_t)f2bf((v0.x - mu) * rstd * g0.x + b0.x) |
                ((uint32_t)f2bf((v0.y - mu) * rstd * g0.y + b0.y) << 16);
  uint32_t w1 = (uint32_t)f2bf((v0.z - mu) * rstd * g0.z + b0.z) |
                ((uint32_t)f2bf((v0.w - mu) * rstd * g0.w + b0.w) << 16);
  uint32_t w2 = (uint32_t)f2bf((v1.x - mu) * rstd * g1.x + b1.x) |
                ((uint32_t)f2bf((v1.y - mu) * rstd * g1.y + b1.y) << 16);
  uint32_t w3 = (uint32_t)f2bf((v1.z - mu) * rstd * g1.z + b1.z) |
                ((uint32_t)f2bf((v1.w - mu) * rstd * g1.w + b1.w) << 16);
  uint4 r; r.x = w0; r.y = w1; r.z = w2; r.w = w3;
  ((uint4*)(o + (size_t)row * D))[lane] = r;
}

// ---------------- W (L,512,1024) fp32 -> Wtrow (L,1024,512) bf16 -------------
__global__ __launch_bounds__(256) void k_convW(const float* __restrict__ W,
                                               unsigned short* __restrict__ Wt) {
  __shared__ float tile[32][33];
  int bid = blockIdx.x;
  int l = bid >> 9;
  int rem = bid & 511;
  int kt = rem >> 5, nt = rem & 31;
  int k0 = kt * 32, n0 = nt * 32;
  int tx = threadIdx.x & 31, ty = threadIdx.x >> 5;   // 32 x 8
  const float* Wl = W + (size_t)l * D * 2 * D;
  for (int i = 0; i < 4; i++) {
    int k = k0 + ty + 8 * i;
    tile[ty + 8 * i][tx] = Wl[(size_t)k * 1024 + n0 + tx];
  }
  __syncthreads();
  unsigned short* Wtl = Wt + (size_t)l * 1024 * D;
  for (int i = 0; i < 4; i++) {
    int n = n0 + ty + 8 * i;
    Wtl[(size_t)n * D + k0 + tx] = f2bf(tile[tx][ty + 8 * i]);
  }
}

// ---------------- Wtrow -> B-fragment-ordered WtF ----------------------------
__global__ __launch_bounds__(256) void k_fragW(const unsigned short* __restrict__ Wt,
                                               unsigned short* __restrict__ WtF) {
  int t = blockIdx.x * 256 + threadIdx.x;
  int lane = t & 63;
  int tile = t >> 6;                 // 0 .. 12*1024-1
  int l = tile >> 10;
  int rem = tile & 1023;
  int n16 = rem >> 4, kt = rem & 15;
  const unsigned short* src = Wt + (size_t)l * 1024 * 512 +
                              (size_t)(n16 * 16 + (lane & 15)) * 512 + kt * 32 + (lane >> 4) * 8;
  *(uint4*)(WtF + (size_t)l * 524288 + ((size_t)rem * 64 + lane) * 8) = *(const uint4*)src;
}

// ---------------- emb fp32 -> bf16 (row-major, for logits GEMM) --------------
__global__ __launch_bounds__(256) void k_convEmb(const float* __restrict__ e,
                                                 unsigned short* __restrict__ o) {
  int t = blockIdx.x * 256 + threadIdx.x;
  const float4* s = (const float4*)e + (size_t)t * 2;
  float4 a = s[0], b = s[1];
  uint32_t w0 = (uint32_t)f2bf(a.x) | ((uint32_t)f2bf(a.y) << 16);
  uint32_t w1 = (uint32_t)f2bf(a.z) | ((uint32_t)f2bf(a.w) << 16);
  uint32_t w2 = (uint32_t)f2bf(b.x) | ((uint32_t)f2bf(b.y) << 16);
  uint32_t w3 = (uint32_t)f2bf(b.z) | ((uint32_t)f2bf(b.w) << 16);
  uint4 r; r.x = w0; r.y = w1; r.z = w2; r.w = w3;
  ((uint4*)o)[t] = r;
}

// ---------------- mega kernel: apply(l-1) + LN + GEMM + act + (y,F) + (P,Q) --
// Staging (APPLY=1): per wave-row: x_new = x + y + F*h_in (elementwise, from
// previous layer's yF + Hs), write x, LN -> write hbf (plain row-major, same
// layout as the old k_ln output), s_waitcnt vmcnt(0), then the VERIFIED
// gl_lds16 swizzled staging re-reads hbf (same-wave RAW through L2).
// Epilogue: per-element exclusive-prefix scan -> (F_s, y_s) packed f16 into
// yF, plus chunk totals (P,Q) for scan2. Replaces the old fv/scan3 pair.
__global__ __launch_bounds__(256, 2) void k_gemm_act(float* __restrict__ X,
                                                     uint32_t* __restrict__ yF,
                                                     const float* __restrict__ Hs,
                                                     const float* __restrict__ lng,
                                                     const float* __restrict__ lnb,
                                                     unsigned short* __restrict__ Ah,
                                                     const unsigned short* __restrict__ Bt,
                                                     float* __restrict__ P,
                                                     float* __restrict__ Q,
                                                     int APPLY) {
  __shared__ __align__(16) unsigned short As[64 * 512];   // 64 KiB
  const int tid = threadIdx.x;
  const int lane = tid & 63;
  const int wave = tid >> 6;
  const int m0 = blockIdx.x * 64;
  const int qm = lane & 15;
  const int hi = lane >> 4;          // 0..3
  const int b_loc = m0 >> 13;              // batch within group
  const int c_chunk = (m0 & (SS - 1)) >> 6;
  const size_t pq0 = ((size_t)b_loc * CH + c_chunk) * 512;

  if (APPLY) {
    // h_in for this chunk, lane's 8 columns (cols lane*8..+7)
    const float4* hp = (const float4*)(Hs + pq0) + lane * 2;
    float4 h0v = hp[0], h1v = hp[1];
    const float4* gp = (const float4*)lng + lane * 2;
    const float4* bp = (const float4*)lnb + lane * 2;
    float4 gg0 = gp[0], gg1 = gp[1], bb0 = bp[0], bb1 = bp[1];
    for (int j = 0; j < 16; j++) {
      size_t row = (size_t)(m0 + wave * 16 + j);
      float4* xp = (float4*)(X + row * 512) + lane * 2;
      float4 x0 = xp[0], x1 = xp[1];
      const uint4* yp = (const uint4*)(yF + row * 512) + lane * 2;
      uint4 y0 = yp[0], y1 = yp[1];
      float Ff, yy;
      unpack_fv(y0.x, Ff, yy); x0.x += yy + Ff * h0v.x;
      unpack_fv(y0.y, Ff, yy); x0.y += yy + Ff * h0v.y;
      unpack_fv(y0.z, Ff, yy); x0.z += yy + Ff * h0v.z;
      unpack_fv(y0.w, Ff, yy); x0.w += yy + Ff * h0v.w;
      unpack_fv(y1.x, Ff, yy); x1.x += yy + Ff * h1v.x;
      unpack_fv(y1.y, Ff, yy); x1.y += yy + Ff * h1v.y;
      unpack_fv(y1.z, Ff, yy); x1.z += yy + Ff * h1v.z;
      unpack_fv(y1.w, Ff, yy); x1.w += yy + Ff * h1v.w;
      xp[0] = x0; xp[1] = x1;
      // LN of the updated row (verified k_ln body)
      float sm = x0.x + x0.y + x0.z + x0.w + x1.x + x1.y + x1.z + x1.w;
      float ss = x0.x * x0.x + x0.y * x0.y + x0.z * x0.z + x0.w * x0.w +
                 x1.x * x1.x + x1.y * x1.y + x1.z * x1.z + x1.w * x1.w;
      for (int m = 32; m; m >>= 1) {
        sm += __shfl_xor(sm, m, 64);
        ss += __shfl_xor(ss, m, 64);
      }
      float mu = sm * (1.0f / 512.0f);
      float var = ss * (1.0f / 512.0f) - mu * mu;
      float rstd = rsqrtf(var + 1e-5f);
      uint32_t w0 = (uint32_t)f2bf((x0.x - mu) * rstd * gg0.x + bb0.x) |
                    ((uint32_t)f2bf((x0.y - mu) * rstd * gg0.y + bb0.y) << 16);
      uint32_t w1 = (uint32_t)f2bf((x0.z - mu) * rstd * gg0.z + bb0.z) |
                    ((uint32_t)f2bf((x0.w - mu) * rstd * gg0.w + bb0.w) << 16);
      uint32_t w2 = (uint32_t)f2bf((x1.x - mu) * rstd * gg1.x + bb1.x) |
                    ((uint32_t)f2bf((x1.y - mu) * rstd * gg1.y + bb1.y) << 16);
      uint32_t w3 = (uint32_t)f2bf((x1.z - mu) * rstd * gg1.z + bb1.z) |
                    ((uint32_t)f2bf((x1.w - mu) * rstd * gg1.w + bb1.w) << 16);
      uint4 rr; rr.x = w0; rr.y = w1; rr.z = w2; rr.w = w3;
      ((uint4*)(Ah + row * 512))[lane] = rr;
    }
    // drain stores so the gl_lds16 re-read (same wave, same rows) sees them
    asm volatile("s_waitcnt vmcnt(0)" ::: "memory");
    __builtin_amdgcn_sched_barrier(0);
  }

  // ---- stage A from hbf: one row per inst, chunk-swizzled (verified path)
  for (int j = 0; j < 16; j++) {
    int r = wave * 16 + j;
    int cg = (lane & ~7) | ((lane & 7) ^ (r & 7));
    gl_lds16(Ah + (size_t)(m0 + r) * 512 + cg * 8, As + r * 512);
  }
  __syncthreads();

  for (int np = 0; np < 2; np++) {
    const int c0 = np * 256 + wave * 64;   // hidden col base for this wave
    const int n16h = (c0 >> 4);            // + j ; gate = +32
    f32x4 ah[4][4] = {};
    f32x4 ag[4][4] = {};
    bf16x8 bh[2][4], bg[2][4];
    for (int j = 0; j < 4; j++) {
      bh[0][j] = *(const bf16x8*)(Bt + (((size_t)(n16h + j) * 16 + 0) * 64 + lane) * 8);
      bg[0][j] = *(const bf16x8*)(Bt + (((size_t)(n16h + j + 32) * 16 + 0) * 64 + lane) * 8);
    }
    for (int kt = 0; kt < 16; kt++) {
      const int cur = kt & 1;
      if (kt < 15) {
        const int nxt = cur ^ 1;
        for (int j = 0; j < 4; j++) {
          bh[nxt][j] = *(const bf16x8*)(Bt + (((size_t)(n16h + j) * 16 + kt + 1) * 64 + lane) * 8);
          bg[nxt][j] = *(const bf16x8*)(Bt + (((size_t)(n16h + j + 32) * 16 + kt + 1) * 64 + lane) * 8);
        }
      }
      bf16x8 af[4];
      for (int i = 0; i < 4; i++) {
        int row = i * 16 + qm;
        int cgd = kt * 4 + hi;
        int cl = (cgd & ~7) | ((cgd & 7) ^ (row & 7));
        af[i] = *(const bf16x8*)(&As[row * 512 + cl * 8]);
      }
      for (int i = 0; i < 4; i++)
        for (int j = 0; j < 4; j++) {
          ah[i][j] = __builtin_amdgcn_mfma_f32_16x16x32_bf16(af[i], bh[cur][j], ah[i][j], 0, 0, 0);
          ag[i][j] = __builtin_amdgcn_mfma_f32_16x16x32_bf16(af[i], bg[cur][j], ag[i][j], 0, 0, 0);
        }
    }
    // ---- epilogue: activation + per-element (F_s, y_s) + chunk (P,Q)
    const int rq = hi * 4;
    for (int j = 0; j < 4; j++) {
      float Bp = 1.f, Bq = 0.f;                 // prefix of rows < i*16
      for (int i = 0; i < 4; i++) {
        float fr[4], vr[4];
        float sp = 1.f, sq = 0.f;
#pragma unroll
        for (int r = 0; r < 4; r++) {
          float h = ah[i][j][r];
          float g = ag[i][j][r];
          float e = __expf(g);
          float f = rcpf_(1.0f + e);
          float sg = 1.0f - f;
          float gf = h >= 0.0f ? h + 0.5f : rcpf_(1.0f + __expf(-h));
          float v = sg * gf;
          fr[r] = f; vr[r] = v;
          sq = sq * f + v;
          sp *= f;
        }
        // inclusive Kogge-Stone over the 4 hi groups (rows i*16 + hi*4 + r)
        float Ip = sp, Iq = sq;
        float tp = __shfl_up(Ip, 16, 64), tq = __shfl_up(Iq, 16, 64);
        if (hi >= 1) { Iq = tq * Ip + Iq; Ip = tp * Ip; }
        tp = __shfl_up(Ip, 32, 64); tq = __shfl_up(Iq, 32, 64);
        if (hi >= 2) { Iq = tq * Ip + Iq; Ip = tp * Ip; }
        // exclusive group prefix
        float Ep = __shfl_up(Ip, 16, 64), Eq = __shfl_up(Iq, 16, 64);
        if (hi == 0) { Ep = 1.f; Eq = 0.f; }
        // block-i total (inclusive at hi==3)
        float Tp = __shfl(Ip, 48 + qm, 64), Tq = __shfl(Iq, 48 + qm, 64);
        // prefix entering this lane's 4 rows: compose(B, E)
        float yv = Bq * Ep + Eq;
        float Fv = Bp * Ep;
#pragma unroll
        for (int r = 0; r < 4; r++) {
          yv = fr[r] * yv + vr[r];
          Fv = Fv * fr[r];
          int rowg = m0 + i * 16 + rq + r;
          yF[(size_t)rowg * 512 + c0 + j * 16 + qm] = pack_fv(Fv, yv);
        }
        Bq = Bq * Tp + Tq;
        Bp = Bp * Tp;
      }
      if (hi == 0) {
        P[pq0 + c0 + j * 16 + qm] = Bp;
        Q[pq0 + c0 + j * 16 + qm] = Bq;
      }
    }
  }
}

// ---------------- logits GEMM: C = A * Bt^T ---------------------------------
__global__ __launch_bounds__(256) void k_gemm(const unsigned short* __restrict__ A,
                                              const unsigned short* __restrict__ Bt,
                                              float* __restrict__ C, int N, int MT) {
  __shared__ __align__(16) unsigned short As[128 * 64];
  __shared__ __align__(16) unsigned short Bs[128 * 64];
  const int tid = threadIdx.x;
  const int lane = tid & 63;
  const int wave = tid >> 6;
  const int bid = blockIdx.x;
  const int mt = bid % MT;
  const int nt = bid / MT;
  const int m0 = mt * 128, n0 = nt * 128;
  const int wr = (wave >> 1) * 64;
  const int wc = (wave & 1) * 64;
  const int lrow = lane >> 3;
  const int lcs = ((lane & 7) ^ lrow) * 8;
  const unsigned short* Ag = A + (size_t)(m0 + wave * 32 + lrow) * 512 + lcs;
  const unsigned short* Bg = Bt + (size_t)(n0 + wave * 32 + lrow) * 512 + lcs;
  unsigned short* Al = As + wave * 32 * 64;
  unsigned short* Bl = Bs + wave * 32 * 64;
  const int qm = lane & 15;
  const int hi = lane >> 4;
  f32x4 acc[4][4] = {};
  for (int k0 = 0; k0 < 512; k0 += 64) {
    for (int j = 0; j < 4; j++) gl_lds16(Ag + k0 + (size_t)j * 8 * 512, Al + j * 512);
    for (int j = 0; j < 4; j++) gl_lds16(Bg + k0 + (size_t)j * 8 * 512, Bl + j * 512);
    __syncthreads();
    for (int ks = 0; ks < 2; ks++) {
      const int sw = ((ks * 4 + hi) ^ (qm & 7)) * 8;
      bf16x8 af[4], bfr[4];
      for (int i = 0; i < 4; i++) {
        af[i] = *(const bf16x8*)(&As[(wr + i * 16 + qm) * 64 + sw]);
        bfr[i] = *(const bf16x8*)(&Bs[(wc + i * 16 + qm) * 64 + sw]);
      }
      for (int i = 0; i < 4; i++)
        for (int j = 0; j < 4; j++)
          acc[i][j] = __builtin_amdgcn_mfma_f32_16x16x32_bf16(af[i], bfr[j], acc[i][j], 0, 0, 0);
    }
    __syncthreads();
  }
  const int col = lane & 15;
  const int rq = (lane >> 4) * 4;
  for (int i = 0; i < 4; i++)
    for (int j = 0; j < 4; j++)
      for (int r = 0; r < 4; r++)
        C[(size_t)(m0 + wr + i * 16 + rq + r) * N + (n0 + wc + j * 16 + col)] = acc[i][j][r];
}

// ---------------- scan phase 2: hierarchical parallel chunk-prefix -----------
__global__ __launch_bounds__(512) void k_scan2(const float* __restrict__ P,
                                               const float* __restrict__ Q,
                                               float* __restrict__ Hs) {
  __shared__ float lp[8][64];
  __shared__ float lq[8][64];
  const int lane = threadIdx.x & 63;
  const int w = threadIdx.x >> 6;          // 0..7
  const int dg = blockIdx.x & 7;           // d-group (D/64 = 8)
  const int b = blockIdx.x >> 3;
  const int d = dg * 64 + lane;
  const int c0 = w * 16;                   // CH/8 = 16 chunks per wave
  const size_t base = (size_t)b * CH * 512 + d;
  float p = 1.f, q = 0.f;
  for (int c = c0; c < c0 + 16; c++) {
    size_t i = base + (size_t)c * 512;
    float Pc = P[i], Qc = Q[i];
    q = q * Pc + Qc;
    p = p * Pc;
  }
  lp[w][lane] = p;
  lq[w][lane] = q;
  __syncthreads();
  float qq = 0.f;
  for (int ww = 0; ww < w; ww++) {
    float a = lp[ww][lane], bq = lq[ww][lane];
    qq = qq * a + bq;
  }
  float h = qq;                            // h entering chunk c0 (h_init = 0)
  for (int c = c0; c < c0 + 16; c++) {
    size_t i = base + (size_t)c * 512;
    Hs[i] = h;
    h = P[i] * h + Q[i];
  }
}

// ---------------- final apply + residual + final LayerNorm -------------------
// scan3 structure with the serial recurrence replaced by the elementwise
// (F,y) apply. Runs ONCE (after layer 11) with norm_g/norm_b.
__global__ __launch_bounds__(512) void k_apply_ln(const uint32_t* __restrict__ yF,
                                                  const float* __restrict__ Hs,
                                                  float* __restrict__ x,
                                                  const float* __restrict__ g,
                                                  const float* __restrict__ b,
                                                  unsigned short* __restrict__ o) {
  const int d = threadIdx.x;               // 0..511
  const int bc = blockIdx.x;               // b*CH + c
  const int c = bc & (CH - 1);
  const int bb = bc >> 7;                  // CH = 128
  const size_t row0 = ((size_t)bb * SS + (size_t)c * SL);
  const uint32_t* base = yF + row0 * 512 + d;
  float* xb = x + row0 * 512 + d;
  float h = Hs[(size_t)bc * 512 + d];
  for (int s = 0; s < SL; s++) {
    float F, y;
    unpack_fv(base[(size_t)s * 512], F, y);
    xb[(size_t)s * 512] += y + F * h;
  }
  __syncthreads();   // block's x-rows complete & visible (workgroup scope)

  const int wv = threadIdx.x >> 6, lane = threadIdx.x & 63;
  const float4* gp = (const float4*)g + lane * 2;
  const float4* bp = (const float4*)b + lane * 2;
  float4 g0 = gp[0], g1 = gp[1], b0 = bp[0], b1 = bp[1];
  const float* xr0 = x + row0 * 512;
  for (int rr = 0; rr < 8; rr++) {
    int r = wv * 8 + rr;
    const float4* xr = (const float4*)(xr0 + (size_t)r * 512) + lane * 2;
    float4 v0 = xr[0], v1 = xr[1];
    float sm = v0.x + v0.y + v0.z + v0.w + v1.x + v1.y + v1.z + v1.w;
    float ss = v0.x * v0.x + v0.y * v0.y + v0.z * v0.z + v0.w * v0.w +
               v1.x * v1.x + v1.y * v1.y + v1.z * v1.z + v1.w * v1.w;
    for (int m = 32; m; m >>= 1) {
      sm += __shfl_xor(sm, m, 64);
      ss += __shfl_xor(ss, m, 64);
    }
    float mu = sm * (1.0f / 512.0f);
    float var = ss * (1.0f / 512.0f) - mu * mu;
    float rstd = rsqrtf(var + 1e-5f);
    uint32_t w0 = (uint32_t)f2bf((v0.x - mu) * rstd * g0.x + b0.x) |
                  ((uint32_t)f2bf((v0.y - mu) * rstd * g0.y + b0.y) << 16);
    uint32_t w1 = (uint32_t)f2bf((v0.z - mu) * rstd * g0.z + b0.z) |
                  ((uint32_t)f2bf((v0.w - mu) * rstd * g0.w + b0.w) << 16);
    uint32_t w2 = (uint32_t)f2bf((v1.x - mu) * rstd * g1.x + b1.x) |
                  ((uint32_t)f2bf((v1.y - mu) * rstd * g1.y + b1.y) << 16);
    uint32_t w3 = (uint32_t)f2bf((v1.z - mu) * rstd * g1.z + b1.z) |
                  ((uint32_t)f2bf((v1.w - mu) * rstd * g1.w + b1.w) << 16);
    uint4 rr4; rr4.x = w0; rr4.y = w1; rr4.z = w2; rr4.w = w3;
    ((uint4*)(o + (row0 + r) * 512))[lane] = rr4;
  }
}

extern "C" void kernel_launch(void* const* d_in, const int* in_sizes, int n_in,
                              void* d_out, int out_size, void* d_ws, size_t ws_size,
                              hipStream_t stream) {
  const int* toks = (const int*)d_in[0];
  const float* emb = (const float*)d_in[1];
  const float* ln_g = (const float*)d_in[2];
  const float* ln_b = (const float*)d_in[3];
  const float* W = (const float*)d_in[4];
  const float* norm_g = (const float*)d_in[5];
  const float* norm_b = (const float*)d_in[6];
  float* out = (float*)d_out;   // fp32 logits

  // Batch-group ladder; ws_size constant across calls -> graph-safe.
  const int gbs[4] = {8, 4, 2, 1};
  int GB = 1;
  for (int i = 0; i < 4; i++) {
    size_t MGv = (size_t)gbs[i] * SS;
    size_t need = MGv * 5120 + 2 * 12582912 + 262144 + (size_t)gbs[i] * 786432;
    if (need <= ws_size) { GB = gbs[i]; break; }
  }
  const int MG = GB * SS;        // rows per group
  const int MT128 = MG / 128;    // 128-row m-tiles (logits gemm)

  char* p = (char*)d_ws;
  float* x = (float*)p;                     p += (size_t)MG * 2048;
  uint32_t* yF = (uint32_t*)p;              p += (size_t)MG * 2048;
  unsigned short* hbf = (unsigned short*)p; p += (size_t)MG * 1024;
  unsigned short* Wtrow = (unsigned short*)p; p += 12582912;
  unsigned short* WtF = (unsigned short*)p;   p += 12582912;
  unsigned short* ebf = (unsigned short*)p;   p += 262144;
  float* P = (float*)p;                     p += (size_t)GB * 262144;
  float* Q = (float*)p;                     p += (size_t)GB * 262144;
  float* Hs = (float*)p;

  k_convW<<<NLAYER * 512, 256, 0, stream>>>(W, Wtrow);
  k_fragW<<<NLAYER * 1024 * 64 / 256, 256, 0, stream>>>(Wtrow, WtF);
  k_convEmb<<<64, 256, 0, stream>>>(emb, ebf);

  for (int g = 0; g < BB / GB; g++) {
    const int* tg = toks + (size_t)g * MG;
    float* outg = out + (size_t)g * MG * VOCAB;

    // gather + LN(layer 0) -> x, hbf
    k_gather<<<MG / 4, 256, 0, stream>>>(tg, emb, ln_g, ln_b, x, hbf);
    for (int l = 0; l < NLAYER; l++) {
      k_gemm_act<<<MG / 64, 256, 0, stream>>>(x, yF, Hs,
                                              ln_g + (size_t)l * D, ln_b + (size_t)l * D,
                                              hbf, WtF + (size_t)l * 524288, P, Q,
                                              l > 0 ? 1 : 0);
      k_scan2<<<GB * 8, 512, 0, stream>>>(P, Q, Hs);
    }
    k_apply_ln<<<GB * CH, 512, 0, stream>>>(yF, Hs, x, norm_g, norm_b, hbf);
    k_gemm<<<2 * MT128, 256, 0, stream>>>(hbf, ebf, outg, VOCAB, MT128);
  }
}